// Round 6
// baseline (287.419 us; speedup 1.0000x reference)
//
#include <hip/hip_runtime.h>

// Product quantizer: N=16384, D=1024, M=64 subspaces, K=256 codes, d=16.
// Scores s = x·c - 0.5||c||^2 via split-bf16 MFMA (ch·xh + cl·xh + ch·xl, |err|~1e-4;
// argmax == argmin dist). Codebook hi/lo/norms in LDS (no per-thread arrays -> no
// spill; verified R5). Tracking uses score-with-packed-index (8-bit code in low
// mantissa bits): best/sec/argmax are pure max/min chains. Masked-score top-2 gap
// < MARGIN -> LDS-batched flag list -> exact f64 refine (first-min tie-break).
// Packing error <= |s|*1.5e-5; exact masked ties -> gap 0 -> flagged -> refined.

#define NROWS  16384
#define DIMS   1024
#define MSUB   64
#define KCODE  256
#define DSUB   16
#define FLCAP  128

static constexpr float MARGIN = 5e-3f;

typedef __attribute__((ext_vector_type(4))) short s16x4;
typedef __attribute__((ext_vector_type(4))) float f32x4;

static __device__ __forceinline__ short f2bf(float f) {
    unsigned u = __float_as_uint(f);
    u += 0x7fffu + ((u >> 16) & 1u);          // RNE to bf16
    return (short)(u >> 16);
}
static __device__ __forceinline__ float bf2f(short h) {
    return __uint_as_float(((unsigned)(unsigned short)h) << 16);
}
static __device__ __forceinline__ float packf(float s, int code) {
    return __uint_as_float((__float_as_uint(s) & 0xFFFFFF00u) | (unsigned)code);
}

static __device__ __forceinline__ f32x4 mfma16(s16x4 a, s16x4 b, f32x4 c) {
#if __has_builtin(__builtin_amdgcn_mfma_f32_16x16x16bf16_1k)
    return __builtin_amdgcn_mfma_f32_16x16x16bf16_1k(a, b, c, 0, 0, 0);
#else
    asm("v_mfma_f32_16x16x16_bf16 %0, %1, %2, %0" : "+v"(c) : "v"(a), "v"(b));
    return c;
#endif
}

// Block = 256 threads = 4 waves, one m per block, 512 rows per block (wave: 128 rows
// = 8 tiles of 16). Grid 2048 = 64 m x 32 row-groups, XCD-grouped by row-group.
// LDS ~17.9KB; VGPR cap 85 via launch_bounds -> ~6 blocks/CU resident.
__global__ __launch_bounds__(256, 6) void pq_main(
    const float* __restrict__ embeds,
    const float* __restrict__ codebooks,
    float* __restrict__ out,
    unsigned* __restrict__ flag_cnt,
    unsigned* __restrict__ flag_list,
    unsigned flag_cap)
{
    __shared__ short chi[KCODE * DSUB];   // 8KB: bf16 hi of codebook[m], MFMA-frag order
    __shared__ short clo[KCODE * DSUB];   // 8KB: bf16 lo residual
    __shared__ float cnorm[KCODE];        // 1KB: -0.5*||c||^2
    __shared__ unsigned fl_buf[FLCAP];    // block-local flag queue
    __shared__ unsigned fl_cnt, fl_base;

    const int tid = threadIdx.x;
    const int bid = blockIdx.x;
    const int m   = (bid >> 3) & 63;                  // subspace
    const int g   = (bid & 7) | ((bid >> 9) << 3);    // row-group (0..31), XCD-grouped
    const float* cbm = codebooks + (size_t)m * (KCODE * DSUB);

    if (tid == 0) fl_cnt = 0;

    // ---- Stage codebook[m]: thread tid owns code tid (contiguous 16KB read) ----
    {
        const float4* src = (const float4*)(cbm + tid * DSUB);
        float c[16];
        #pragma unroll
        for (int q = 0; q < 4; ++q) {
            float4 v = src[q];
            c[4*q+0] = v.x; c[4*q+1] = v.y; c[4*q+2] = v.z; c[4*q+3] = v.w;
        }
        float ss = 0.f;
        s16x4* chv = (s16x4*)chi + tid * 4;
        s16x4* clv = (s16x4*)clo + tid * 4;
        #pragma unroll
        for (int q = 0; q < 4; ++q) {
            short h0 = f2bf(c[4*q+0]), h1 = f2bf(c[4*q+1]);
            short h2 = f2bf(c[4*q+2]), h3 = f2bf(c[4*q+3]);
            chv[q] = (s16x4){h0, h1, h2, h3};
            clv[q] = (s16x4){f2bf(c[4*q+0] - bf2f(h0)), f2bf(c[4*q+1] - bf2f(h1)),
                             f2bf(c[4*q+2] - bf2f(h2)), f2bf(c[4*q+3] - bf2f(h3))};
            ss = fmaf(c[4*q+0], c[4*q+0], ss); ss = fmaf(c[4*q+1], c[4*q+1], ss);
            ss = fmaf(c[4*q+2], c[4*q+2], ss); ss = fmaf(c[4*q+3], c[4*q+3], ss);
        }
        cnorm[tid] = -0.5f * ss;
    }
    __syncthreads();

    const int w   = tid >> 6;
    const int l   = tid & 63;
    const int col = l & 15;       // embed-row within 16-row tile (MFMA B/C col)
    const int ds  = l >> 4;       // k-segment (dims ds*4..+4); C row-group (codes)
    const int n0  = (g << 9) + (w << 7);   // 128 rows per wave

    const float* xp = embeds + (size_t)(n0 + col) * DIMS + m * DSUB + ds * 4;
    float*       op = out    + (size_t)(n0 + col) * DIMS + m * DSUB + ds * 4;
    const s16x4* chv = (const s16x4*)chi + col * 4 + ds;   // + kt*64 per k-tile
    const s16x4* clv = (const s16x4*)clo + col * 4 + ds;
    const f32x4* hv  = (const f32x4*)cnorm + ds;           // + kt*4 per k-tile
    const int cb4 = ds * 4;

    float4 xv = *(const float4*)xp;

    #pragma unroll 1
    for (int t = 0; t < 8; ++t) {
        // B fragments: x hi/lo (4 dims of row n0+t*16+col)
        s16x4 bh, bl;
        {
            short h0 = f2bf(xv.x), h1 = f2bf(xv.y), h2 = f2bf(xv.z), h3 = f2bf(xv.w);
            bh = (s16x4){h0, h1, h2, h3};
            bl = (s16x4){f2bf(xv.x - bf2f(h0)), f2bf(xv.y - bf2f(h1)),
                         f2bf(xv.z - bf2f(h2)), f2bf(xv.w - bf2f(h3))};
        }
        if (t < 7) xv = *(const float4*)(xp + (size_t)(t + 1) * 16 * DIMS);

        float best = -3e38f, sec = -3e38f;   // packed score|code chains

        #pragma unroll
        for (int kt = 0; kt < 16; ++kt) {
            f32x4 acc = hv[kt * 4];            // -0.5||c||^2 for this lane's 4 codes
            s16x4 ah = chv[kt * 64];
            s16x4 al = clv[kt * 64];
            acc = mfma16(ah, bh, acc);         // ch·xh
            acc = mfma16(al, bh, acc);         // cl·xh
            acc = mfma16(ah, bl, acc);         // ch·xl
            #pragma unroll
            for (int r = 0; r < 4; ++r) {
                float p = packf(acc[r], kt * 16 + cb4 + r);
                sec  = fmaxf(sec, fminf(p, best));
                best = fmaxf(best, p);
            }
        }

        // Combine the 4 code-partitions (xor 16, 32): all lanes of a col agree.
        #pragma unroll
        for (int msk = 16; msk <= 32; msk <<= 1) {
            float ob = __shfl_xor(best, msk);
            float os = __shfl_xor(sec,  msk);
            sec  = fmaxf(fmaxf(sec, os), fminf(best, ob));
            best = fmaxf(best, ob);
        }

        const int idx = (int)(__float_as_uint(best) & 255u);

        // Exact f32 codeword gather (L1-hot) + 64B-chunk store.
        const float4 cv = *(const float4*)(cbm + (size_t)idx * DSUB + cb4);
        *(float4*)(op + (size_t)t * 16 * DIMS) = cv;

        if (ds == 0) {
            const float bs = __uint_as_float(__float_as_uint(best) & 0xFFFFFF00u);
            const float ss = __uint_as_float(__float_as_uint(sec)  & 0xFFFFFF00u);
            if (bs - ss < MARGIN) {
                unsigned ent = (unsigned)((n0 + t * 16 + col) * 64 + m);
                unsigned p = atomicAdd(&fl_cnt, 1u);          // LDS atomic (cheap)
                if (p < FLCAP) fl_buf[p] = ent;
                else {                                        // rare: safe fallback
                    unsigned q = atomicAdd(flag_cnt, 1u);
                    if (q < flag_cap) flag_list[q] = ent;
                }
            }
        }
    }

    // ---- One global atomic per block; coalesced flag flush ----
    __syncthreads();
    unsigned c = fl_cnt; if (c > FLCAP) c = FLCAP;
    if (tid == 0) fl_base = atomicAdd(flag_cnt, c);
    __syncthreads();
    const unsigned base = fl_base;
    for (unsigned i = tid; i < c; i += 256) {
        unsigned p = base + i;
        if (p < flag_cap) flag_list[p] = fl_buf[i];
    }
}

// One wave per flagged (n,m): exact f64 distances, first-min tie-break.
__global__ __launch_bounds__(256) void pq_refine(
    const float* __restrict__ embeds,
    const float* __restrict__ codebooks,
    float* __restrict__ out,
    const unsigned* __restrict__ flag_cnt,
    const unsigned* __restrict__ flag_list,
    unsigned flag_cap)
{
    unsigned cnt = *flag_cnt;
    if (cnt > flag_cap) cnt = flag_cap;
    const int l = threadIdx.x & 63;
    const unsigned wid = (blockIdx.x << 2) | (unsigned)(threadIdx.x >> 6);
    const unsigned nw  = gridDim.x << 2;

    for (unsigned i = wid; i < cnt; i += nw) {
        const unsigned e = flag_list[i];
        const int n = (int)(e >> 6), m = (int)(e & 63u);
        const float* xrow = embeds + (size_t)n * DIMS + m * DSUB;
        double xd[DSUB];
        #pragma unroll
        for (int dd = 0; dd < DSUB; ++dd) xd[dd] = (double)xrow[dd];
        const float* cbm = codebooks + (size_t)m * (KCODE * DSUB);

        double bd = 1e300;
        int bi = 0;
        #pragma unroll 1
        for (int cc = 0; cc < 4; ++cc) {
            const int c = l * 4 + cc;                 // lane-local ascending
            const float* cp = cbm + c * DSUB;
            double s = 0.0;
            #pragma unroll
            for (int dd = 0; dd < DSUB; ++dd) {
                double diff = xd[dd] - (double)cp[dd];
                s = fma(diff, diff, s);
            }
            if (s < bd) { bd = s; bi = c; }
        }
        #pragma unroll
        for (int msk = 1; msk <= 32; msk <<= 1) {
            double ob = __shfl_xor(bd, msk);
            int   oi  = __shfl_xor(bi, msk);
            if (ob < bd || (ob == bd && oi < bi)) { bd = ob; bi = oi; }
        }
        if (l < DSUB) out[(size_t)n * DIMS + m * DSUB + l] = cbm[bi * DSUB + l];
    }
}

extern "C" void kernel_launch(void* const* d_in, const int* in_sizes, int n_in,
                              void* d_out, int out_size, void* d_ws, size_t ws_size,
                              hipStream_t stream)
{
    const float* embeds    = (const float*)d_in[0];
    const float* codebooks = (const float*)d_in[1];
    float* out = (float*)d_out;

    unsigned* flag_cnt  = (unsigned*)d_ws;
    unsigned* flag_list = (unsigned*)d_ws + 4;   // 16B offset
    unsigned flag_cap = 0;
    if (ws_size >= 32) {
        size_t cap = (ws_size - 16) / sizeof(unsigned);
        flag_cap = (cap > 0x7FFFFFFFull) ? 0x7FFFFFFFu : (unsigned)cap;
    }

    hipMemsetAsync(d_ws, 0, 16, stream);

    pq_main<<<dim3(2048), dim3(256), 0, stream>>>(
        embeds, codebooks, out, flag_cnt, flag_list, flag_cap);

    pq_refine<<<dim3(1024), dim3(256), 0, stream>>>(
        embeds, codebooks, out, flag_cnt, flag_list, flag_cap);
}

// Round 7
// 101.411 us; speedup vs baseline: 2.8342x; 2.8342x over previous
//
#include <hip/hip_runtime.h>

// Product quantizer: N=16384, D=1024, M=64 subspaces, K=256 codes, d=16.
// Scores s = x·c - 0.5||c||^2 via split-bf16 MFMA (ch·xh + cl·xh + ch·xl, |err|~1e-4;
// argmax == argmin dist). Codebook hi/lo/norms in LDS (no per-thread arrays -> no
// spill; R5-verified). Tracking: 8-bit code packed into low mantissa bits, 4
// independent best/sec max-chains (ILP) merged after the k-loop. Masked top-2 gap
// < MARGIN -> LDS-batched flag list -> exact f64 refine (first-min tie-break).
// NOTE: __launch_bounds__ min-waves MUST stay <=2: (256,6) caps VGPR at 40 and
// spills catastrophically (R6: WRITE 236MB, FETCH 720MB, 3.2x slower).

#define NROWS  16384
#define DIMS   1024
#define MSUB   64
#define KCODE  256
#define DSUB   16
#define FLCAP  128

static constexpr float MARGIN = 5e-3f;

typedef __attribute__((ext_vector_type(4))) short s16x4;
typedef __attribute__((ext_vector_type(4))) float f32x4;

static __device__ __forceinline__ short f2bf(float f) {
    unsigned u = __float_as_uint(f);
    u += 0x7fffu + ((u >> 16) & 1u);          // RNE to bf16
    return (short)(u >> 16);
}
static __device__ __forceinline__ float bf2f(short h) {
    return __uint_as_float(((unsigned)(unsigned short)h) << 16);
}
static __device__ __forceinline__ float packf(float s, int code) {
    return __uint_as_float((__float_as_uint(s) & 0xFFFFFF00u) | (unsigned)code);
}

static __device__ __forceinline__ f32x4 mfma16(s16x4 a, s16x4 b, f32x4 c) {
#if __has_builtin(__builtin_amdgcn_mfma_f32_16x16x16bf16_1k)
    return __builtin_amdgcn_mfma_f32_16x16x16bf16_1k(a, b, c, 0, 0, 0);
#else
    asm("v_mfma_f32_16x16x16_bf16 %0, %1, %2, %0" : "+v"(c) : "v"(a), "v"(b));
    return c;
#endif
}

// Block = 256 threads = 4 waves, one m per block, 512 rows per block (wave: 128 rows
// = 8 tiles of 16). Grid 2048 = 64 m x 32 row-groups, XCD-grouped by row-group.
// LDS ~18.9KB (8/CU cap); VGPR ~84 (6/CU cap) -> ~6 blocks/CU resident.
__global__ __launch_bounds__(256, 2) void pq_main(
    const float* __restrict__ embeds,
    const float* __restrict__ codebooks,
    float* __restrict__ out,
    unsigned* __restrict__ flag_cnt,
    unsigned* __restrict__ flag_list,
    unsigned flag_cap)
{
    __shared__ short chi[KCODE * DSUB];   // 8KB: bf16 hi of codebook[m], MFMA-frag order
    __shared__ short clo[KCODE * DSUB];   // 8KB: bf16 lo residual
    __shared__ float cnorm[KCODE];        // 1KB: -0.5*||c||^2
    __shared__ unsigned fl_buf[FLCAP];    // block-local flag queue
    __shared__ unsigned fl_cnt, fl_base;

    const int tid = threadIdx.x;
    const int bid = blockIdx.x;
    const int m   = (bid >> 3) & 63;                  // subspace
    const int g   = (bid & 7) | ((bid >> 9) << 3);    // row-group (0..31), XCD-grouped
    const float* cbm = codebooks + (size_t)m * (KCODE * DSUB);

    if (tid == 0) fl_cnt = 0;

    // ---- Stage codebook[m]: thread tid owns code tid (contiguous 16KB read) ----
    {
        const float4* src = (const float4*)(cbm + tid * DSUB);
        float c[16];
        #pragma unroll
        for (int q = 0; q < 4; ++q) {
            float4 v = src[q];
            c[4*q+0] = v.x; c[4*q+1] = v.y; c[4*q+2] = v.z; c[4*q+3] = v.w;
        }
        float ss = 0.f;
        s16x4* chv = (s16x4*)chi + tid * 4;
        s16x4* clv = (s16x4*)clo + tid * 4;
        #pragma unroll
        for (int q = 0; q < 4; ++q) {
            short h0 = f2bf(c[4*q+0]), h1 = f2bf(c[4*q+1]);
            short h2 = f2bf(c[4*q+2]), h3 = f2bf(c[4*q+3]);
            chv[q] = (s16x4){h0, h1, h2, h3};
            clv[q] = (s16x4){f2bf(c[4*q+0] - bf2f(h0)), f2bf(c[4*q+1] - bf2f(h1)),
                             f2bf(c[4*q+2] - bf2f(h2)), f2bf(c[4*q+3] - bf2f(h3))};
            ss = fmaf(c[4*q+0], c[4*q+0], ss); ss = fmaf(c[4*q+1], c[4*q+1], ss);
            ss = fmaf(c[4*q+2], c[4*q+2], ss); ss = fmaf(c[4*q+3], c[4*q+3], ss);
        }
        cnorm[tid] = -0.5f * ss;
    }
    __syncthreads();

    const int w   = tid >> 6;
    const int l   = tid & 63;
    const int col = l & 15;       // embed-row within 16-row tile (MFMA B/C col)
    const int ds  = l >> 4;       // k-segment (dims ds*4..+4); C row-group (codes)
    const int n0  = (g << 9) + (w << 7);   // 128 rows per wave

    const float* xp = embeds + (size_t)(n0 + col) * DIMS + m * DSUB + ds * 4;
    float*       op = out    + (size_t)(n0 + col) * DIMS + m * DSUB + ds * 4;
    const s16x4* chv = (const s16x4*)chi + col * 4 + ds;   // + kt*64 per k-tile
    const s16x4* clv = (const s16x4*)clo + col * 4 + ds;
    const f32x4* hv  = (const f32x4*)cnorm + ds;           // + kt*4 per k-tile
    const int cb4 = ds * 4;

    float4 xv = *(const float4*)xp;

    #pragma unroll 1
    for (int t = 0; t < 8; ++t) {
        // B fragments: x hi/lo (4 dims of row n0+t*16+col)
        s16x4 bh, bl;
        {
            short h0 = f2bf(xv.x), h1 = f2bf(xv.y), h2 = f2bf(xv.z), h3 = f2bf(xv.w);
            bh = (s16x4){h0, h1, h2, h3};
            bl = (s16x4){f2bf(xv.x - bf2f(h0)), f2bf(xv.y - bf2f(h1)),
                         f2bf(xv.z - bf2f(h2)), f2bf(xv.w - bf2f(h3))};
        }
        if (t < 7) xv = *(const float4*)(xp + (size_t)(t + 1) * 16 * DIMS);

        // 4 independent packed best/sec chains (one per C register) -> ILP.
        float best[4], sec[4];
        #pragma unroll
        for (int r = 0; r < 4; ++r) { best[r] = -3e38f; sec[r] = -3e38f; }

        #pragma unroll
        for (int kt = 0; kt < 16; ++kt) {
            f32x4 acc = hv[kt * 4];            // -0.5||c||^2 for this lane's 4 codes
            s16x4 ah = chv[kt * 64];
            s16x4 al = clv[kt * 64];
            acc = mfma16(ah, bh, acc);         // ch·xh
            acc = mfma16(al, bh, acc);         // cl·xh
            acc = mfma16(ah, bl, acc);         // ch·xl
            #pragma unroll
            for (int r = 0; r < 4; ++r) {
                float p = packf(acc[r], kt * 16 + cb4 + r);
                sec[r]  = fmaxf(sec[r], fminf(p, best[r]));
                best[r] = fmaxf(best[r], p);
            }
        }

        // Merge 4 chains: top-2 of union.
        float b01 = fmaxf(best[0], best[1]);
        float s01 = fmaxf(fminf(best[0], best[1]), fmaxf(sec[0], sec[1]));
        float b23 = fmaxf(best[2], best[3]);
        float s23 = fmaxf(fminf(best[2], best[3]), fmaxf(sec[2], sec[3]));
        float bb  = fmaxf(b01, b23);
        float ssc = fmaxf(fminf(b01, b23), fmaxf(s01, s23));

        // Combine the 4 code-partitions (xor 16, 32): all lanes of a col agree.
        #pragma unroll
        for (int msk = 16; msk <= 32; msk <<= 1) {
            float ob = __shfl_xor(bb,  msk);
            float os = __shfl_xor(ssc, msk);
            ssc = fmaxf(fmaxf(ssc, os), fminf(bb, ob));
            bb  = fmaxf(bb, ob);
        }

        const int idx = (int)(__float_as_uint(bb) & 255u);

        // Exact f32 codeword gather (L1-hot) + 64B-chunk store.
        const float4 cv = *(const float4*)(cbm + (size_t)idx * DSUB + cb4);
        *(float4*)(op + (size_t)t * 16 * DIMS) = cv;

        if (ds == 0) {
            const float bs = __uint_as_float(__float_as_uint(bb)  & 0xFFFFFF00u);
            const float sm = __uint_as_float(__float_as_uint(ssc) & 0xFFFFFF00u);
            if (bs - sm < MARGIN) {
                unsigned ent = (unsigned)((n0 + t * 16 + col) * 64 + m);
                unsigned p = atomicAdd(&fl_cnt, 1u);          // LDS atomic (cheap)
                if (p < FLCAP) fl_buf[p] = ent;
                else {                                        // rare: safe fallback
                    unsigned q = atomicAdd(flag_cnt, 1u);
                    if (q < flag_cap) flag_list[q] = ent;
                }
            }
        }
    }

    // ---- One global atomic per block; coalesced flag flush ----
    __syncthreads();
    unsigned c = fl_cnt; if (c > FLCAP) c = FLCAP;
    if (tid == 0) fl_base = atomicAdd(flag_cnt, c);
    __syncthreads();
    const unsigned base = fl_base;
    for (unsigned i = tid; i < c; i += 256) {
        unsigned p = base + i;
        if (p < flag_cap) flag_list[p] = fl_buf[i];
    }
}

// One wave per flagged (n,m): exact f64 distances, first-min tie-break.
__global__ __launch_bounds__(256) void pq_refine(
    const float* __restrict__ embeds,
    const float* __restrict__ codebooks,
    float* __restrict__ out,
    const unsigned* __restrict__ flag_cnt,
    const unsigned* __restrict__ flag_list,
    unsigned flag_cap)
{
    unsigned cnt = *flag_cnt;
    if (cnt > flag_cap) cnt = flag_cap;
    const int l = threadIdx.x & 63;
    const unsigned wid = (blockIdx.x << 2) | (unsigned)(threadIdx.x >> 6);
    const unsigned nw  = gridDim.x << 2;

    for (unsigned i = wid; i < cnt; i += nw) {
        const unsigned e = flag_list[i];
        const int n = (int)(e >> 6), m = (int)(e & 63u);
        const float* xrow = embeds + (size_t)n * DIMS + m * DSUB;
        double xd[DSUB];
        #pragma unroll
        for (int dd = 0; dd < DSUB; ++dd) xd[dd] = (double)xrow[dd];
        const float* cbm = codebooks + (size_t)m * (KCODE * DSUB);

        double bd = 1e300;
        int bi = 0;
        #pragma unroll 1
        for (int cc = 0; cc < 4; ++cc) {
            const int c = l * 4 + cc;                 // lane-local ascending
            const float* cp = cbm + c * DSUB;
            double s = 0.0;
            #pragma unroll
            for (int dd = 0; dd < DSUB; ++dd) {
                double diff = xd[dd] - (double)cp[dd];
                s = fma(diff, diff, s);
            }
            if (s < bd) { bd = s; bi = c; }
        }
        #pragma unroll
        for (int msk = 1; msk <= 32; msk <<= 1) {
            double ob = __shfl_xor(bd, msk);
            int   oi  = __shfl_xor(bi, msk);
            if (ob < bd || (ob == bd && oi < bi)) { bd = ob; bi = oi; }
        }
        if (l < DSUB) out[(size_t)n * DIMS + m * DSUB + l] = cbm[bi * DSUB + l];
    }
}

extern "C" void kernel_launch(void* const* d_in, const int* in_sizes, int n_in,
                              void* d_out, int out_size, void* d_ws, size_t ws_size,
                              hipStream_t stream)
{
    const float* embeds    = (const float*)d_in[0];
    const float* codebooks = (const float*)d_in[1];
    float* out = (float*)d_out;

    unsigned* flag_cnt  = (unsigned*)d_ws;
    unsigned* flag_list = (unsigned*)d_ws + 4;   // 16B offset
    unsigned flag_cap = 0;
    if (ws_size >= 32) {
        size_t cap = (ws_size - 16) / sizeof(unsigned);
        flag_cap = (cap > 0x7FFFFFFFull) ? 0x7FFFFFFFu : (unsigned)cap;
    }

    hipMemsetAsync(d_ws, 0, 16, stream);

    pq_main<<<dim3(2048), dim3(256), 0, stream>>>(
        embeds, codebooks, out, flag_cnt, flag_list, flag_cap);

    pq_refine<<<dim3(1024), dim3(256), 0, stream>>>(
        embeds, codebooks, out, flag_cnt, flag_list, flag_cap);
}

// Round 8
// 88.980 us; speedup vs baseline: 3.2302x; 1.1397x over previous
//
#include <hip/hip_runtime.h>

// Product quantizer: N=16384, D=1024, M=64 subspaces, K=256 codes, d=16.
// Scores s = x·c - 0.5||c||^2 (argmax == argmin dist) via split-bf16 16x16x32 MFMA:
//   A = [ch | cl] (codebook hi/lo interleaved, one b128 LDS read),
//   B1 = [xh | xh], B2 = [xl | xl]  ->  acc = A·B1 + A·B2 = full (ch+cl)·(xh+xl).
//   (k-slot pairing: A slot s always multiplies B slot s -> layout-map independent.)
// Two 16-row sub-tiles share each A/hv read (32 rows per kt pass). Tracking packs
// (kt*16+r) into low-8 mantissa bits (compile-time const -> v_and_or), ds*4 added
// once post-loop. Masked top-2 gap < MARGIN -> LDS-batched flag -> exact f64 refine.
// NOTE: __launch_bounds__ min-waves MUST stay <=2: (256,6) caps VGPR at 40 and
// spills catastrophically (R6: WRITE 236MB, FETCH 720MB, 3.2x slower).

#define DIMS   1024
#define MSUB   64
#define KCODE  256
#define DSUB   16
#define FLCAP  128

static constexpr float MARGIN = 2e-3f;

typedef __attribute__((ext_vector_type(8))) short s16x8;
typedef __attribute__((ext_vector_type(4))) float f32x4;
typedef __attribute__((ext_vector_type(4))) unsigned int u32x4;

static __device__ __forceinline__ f32x4 mfma32(s16x8 a, s16x8 b, f32x4 c) {
    return __builtin_amdgcn_mfma_f32_16x16x32_bf16(a, b, c, 0, 0, 0);
}

// Truncation split of 4 floats into duplicated bf16 frags [xh|xh], [xl|xl].
static __device__ __forceinline__ void mk_bfrags(float4 xv, s16x8& B1, s16x8& B2) {
    unsigned u0 = __float_as_uint(xv.x), u1 = __float_as_uint(xv.y);
    unsigned u2 = __float_as_uint(xv.z), u3 = __float_as_uint(xv.w);
    unsigned h01 = (u1 & 0xFFFF0000u) | (u0 >> 16);
    unsigned h23 = (u3 & 0xFFFF0000u) | (u2 >> 16);
    float l0 = xv.x - __uint_as_float(u0 & 0xFFFF0000u);
    float l1 = xv.y - __uint_as_float(u1 & 0xFFFF0000u);
    float l2 = xv.z - __uint_as_float(u2 & 0xFFFF0000u);
    float l3 = xv.w - __uint_as_float(u3 & 0xFFFF0000u);
    unsigned l01 = (__float_as_uint(l1) & 0xFFFF0000u) | (__float_as_uint(l0) >> 16);
    unsigned l23 = (__float_as_uint(l3) & 0xFFFF0000u) | (__float_as_uint(l2) >> 16);
    B1 = __builtin_bit_cast(s16x8, (u32x4){h01, h23, h01, h23});
    B2 = __builtin_bit_cast(s16x8, (u32x4){l01, l23, l01, l23});
}

// Block = 256 threads = 4 waves, one m per block, 512 rows/block (wave: 128 rows =
// 4 passes of 32 rows). Grid 2048 = 64 m x 32 row-groups, XCD-grouped by row-group.
// LDS ~17.6KB; natural VGPR (no forced cap).
__global__ __launch_bounds__(256, 2) void pq_main(
    const float* __restrict__ embeds,
    const float* __restrict__ codebooks,
    float* __restrict__ out,
    unsigned* __restrict__ flag_cnt,
    unsigned* __restrict__ flag_list,
    unsigned flag_cap)
{
    __shared__ u32x4 chcl[16 * 64];       // 16KB: A-frags [kt][col*4+ds] = {ch4 | cl4}
    __shared__ float cnorm[KCODE];        // 1KB: -0.5*||c||^2, code-major
    __shared__ unsigned fl_buf[FLCAP];
    __shared__ unsigned fl_cnt, fl_base;

    const int tid = threadIdx.x;
    const int bid = blockIdx.x;
    const int m   = (bid >> 3) & 63;                  // subspace
    const int g   = (bid & 7) | ((bid >> 9) << 3);    // row-group (0..31), XCD-grouped
    const float* cbm = codebooks + (size_t)m * (KCODE * DSUB);

    if (tid == 0) fl_cnt = 0;

    // ---- Stage codebook[m]: thread tid owns code tid (contiguous 16KB read) ----
    {
        const float4* src = (const float4*)(cbm + tid * DSUB);
        float c[16];
        #pragma unroll
        for (int q = 0; q < 4; ++q) {
            float4 v = src[q];
            c[4*q+0] = v.x; c[4*q+1] = v.y; c[4*q+2] = v.z; c[4*q+3] = v.w;
        }
        float ss = 0.f;
        #pragma unroll
        for (int j = 0; j < 16; ++j) ss = fmaf(c[j], c[j], ss);
        cnorm[tid] = -0.5f * ss;
        #pragma unroll
        for (int d = 0; d < 4; ++d) {
            unsigned uc0 = __float_as_uint(c[4*d+0]), uc1 = __float_as_uint(c[4*d+1]);
            unsigned uc2 = __float_as_uint(c[4*d+2]), uc3 = __float_as_uint(c[4*d+3]);
            unsigned hc01 = (uc1 & 0xFFFF0000u) | (uc0 >> 16);
            unsigned hc23 = (uc3 & 0xFFFF0000u) | (uc2 >> 16);
            float lc0 = c[4*d+0] - __uint_as_float(uc0 & 0xFFFF0000u);
            float lc1 = c[4*d+1] - __uint_as_float(uc1 & 0xFFFF0000u);
            float lc2 = c[4*d+2] - __uint_as_float(uc2 & 0xFFFF0000u);
            float lc3 = c[4*d+3] - __uint_as_float(uc3 & 0xFFFF0000u);
            unsigned lc01 = (__float_as_uint(lc1) & 0xFFFF0000u) | (__float_as_uint(lc0) >> 16);
            unsigned lc23 = (__float_as_uint(lc3) & 0xFFFF0000u) | (__float_as_uint(lc2) >> 16);
            chcl[(tid >> 4) * 64 + (tid & 15) * 4 + d] = (u32x4){hc01, hc23, lc01, lc23};
        }
    }
    __syncthreads();

    const int w   = tid >> 6;
    const int l   = tid & 63;
    const int col = l & 15;       // x-row within 16-row sub-tile (MFMA B/C col)
    const int ds  = l >> 4;       // k-segment / C row-group (codes)
    const int n0  = (g << 9) + (w << 7);   // 128 rows per wave

    const float* xa = embeds + (size_t)(n0 + col) * DIMS + m * DSUB + ds * 4;
    const float* xb = xa + 16 * DIMS;
    float* oa = out + (size_t)(n0 + col) * DIMS + m * DSUB + ds * 4;
    float* ob = oa + 16 * DIMS;
    const u32x4* av  = chcl + col * 4 + ds;            // + kt*64 per k-tile
    const f32x4* hvp = (const f32x4*)cnorm + ds;       // + kt*4 per k-tile
    const unsigned MSK = 0xFFFFFF00u;

    float4 xva = *(const float4*)xa;
    float4 xvb = *(const float4*)xb;

    #pragma unroll 1
    for (int p = 0; p < 4; ++p) {
        s16x8 B1a, B2a, B1b, B2b;
        mk_bfrags(xva, B1a, B2a);
        mk_bfrags(xvb, B1b, B2b);
        if (p < 3) {
            xva = *(const float4*)(xa + (size_t)(p + 1) * 32 * DIMS);
            xvb = *(const float4*)(xb + (size_t)(p + 1) * 32 * DIMS);
        }

        float ba = -3e38f, sa = -3e38f, bb_ = -3e38f, sb = -3e38f;

        #pragma unroll
        for (int kt = 0; kt < 16; ++kt) {
            s16x8 A  = __builtin_bit_cast(s16x8, av[kt * 64]);   // one b128
            f32x4 h  = hvp[kt * 4];                              // broadcast b128
            f32x4 acca = mfma32(A, B1a, h);
            acca = mfma32(A, B2a, acca);
            f32x4 accb = mfma32(A, B1b, h);
            accb = mfma32(A, B2b, accb);
            #pragma unroll
            for (int r = 0; r < 4; ++r) {
                float pa = __uint_as_float((__float_as_uint(acca[r]) & MSK) |
                                           (unsigned)(kt * 16 + r));
                sa = fmaxf(sa, fminf(pa, ba));
                ba = fmaxf(ba, pa);
                float pb = __uint_as_float((__float_as_uint(accb[r]) & MSK) |
                                           (unsigned)(kt * 16 + r));
                sb  = fmaxf(sb, fminf(pb, bb_));
                bb_ = fmaxf(bb_, pb);
            }
        }

        // Fold the lane-constant ds*4 into the packed code (low byte <= 243+12).
        ba  = __uint_as_float(__float_as_uint(ba)  + (unsigned)(ds * 4));
        sa  = __uint_as_float(__float_as_uint(sa)  + (unsigned)(ds * 4));
        bb_ = __uint_as_float(__float_as_uint(bb_) + (unsigned)(ds * 4));
        sb  = __uint_as_float(__float_as_uint(sb)  + (unsigned)(ds * 4));

        // Combine the 4 code-partitions (xor 16, 32): all lanes of a col agree.
        #pragma unroll
        for (int msk = 16; msk <= 32; msk <<= 1) {
            float o1 = __shfl_xor(ba, msk), o2 = __shfl_xor(sa, msk);
            sa = fmaxf(fmaxf(sa, o2), fminf(ba, o1));
            ba = fmaxf(ba, o1);
            float o3 = __shfl_xor(bb_, msk), o4 = __shfl_xor(sb, msk);
            sb  = fmaxf(fmaxf(sb, o4), fminf(bb_, o3));
            bb_ = fmaxf(bb_, o3);
        }

        const int ia = (int)(__float_as_uint(ba)  & 255u);
        const int ib = (int)(__float_as_uint(bb_) & 255u);

        // Exact f32 codeword gather (L1-hot) + 64B-chunk stores (same-XCD lines).
        const float4 cva = *(const float4*)(cbm + (size_t)ia * DSUB + ds * 4);
        const float4 cvb = *(const float4*)(cbm + (size_t)ib * DSUB + ds * 4);
        *(float4*)(oa + (size_t)p * 32 * DIMS) = cva;
        *(float4*)(ob + (size_t)p * 32 * DIMS) = cvb;

        if (ds == 0) {
            float ga = __uint_as_float(__float_as_uint(ba)  & MSK) -
                       __uint_as_float(__float_as_uint(sa)  & MSK);
            float gb = __uint_as_float(__float_as_uint(bb_) & MSK) -
                       __uint_as_float(__float_as_uint(sb)  & MSK);
            if (ga < MARGIN) {
                unsigned ent = (unsigned)((n0 + p * 32 + col) * 64 + m);
                unsigned q = atomicAdd(&fl_cnt, 1u);
                if (q < FLCAP) fl_buf[q] = ent;
                else { unsigned qq = atomicAdd(flag_cnt, 1u);
                       if (qq < flag_cap) flag_list[qq] = ent; }
            }
            if (gb < MARGIN) {
                unsigned ent = (unsigned)((n0 + p * 32 + 16 + col) * 64 + m);
                unsigned q = atomicAdd(&fl_cnt, 1u);
                if (q < FLCAP) fl_buf[q] = ent;
                else { unsigned qq = atomicAdd(flag_cnt, 1u);
                       if (qq < flag_cap) flag_list[qq] = ent; }
            }
        }
    }

    // ---- One global atomic per block; coalesced flag flush ----
    __syncthreads();
    unsigned c = fl_cnt; if (c > FLCAP) c = FLCAP;
    if (tid == 0) fl_base = atomicAdd(flag_cnt, c);
    __syncthreads();
    const unsigned base = fl_base;
    for (unsigned i = tid; i < c; i += 256) {
        unsigned q = base + i;
        if (q < flag_cap) flag_list[q] = fl_buf[i];
    }
}

// One wave per flagged (n,m): exact f64 distances, first-min tie-break.
__global__ __launch_bounds__(256) void pq_refine(
    const float* __restrict__ embeds,
    const float* __restrict__ codebooks,
    float* __restrict__ out,
    const unsigned* __restrict__ flag_cnt,
    const unsigned* __restrict__ flag_list,
    unsigned flag_cap)
{
    unsigned cnt = *flag_cnt;
    if (cnt > flag_cap) cnt = flag_cap;
    const int l = threadIdx.x & 63;
    const unsigned wid = (blockIdx.x << 2) | (unsigned)(threadIdx.x >> 6);
    const unsigned nw  = gridDim.x << 2;

    for (unsigned i = wid; i < cnt; i += nw) {
        const unsigned e = flag_list[i];
        const int n = (int)(e >> 6), m = (int)(e & 63u);
        const float* xrow = embeds + (size_t)n * DIMS + m * DSUB;
        double xd[DSUB];
        #pragma unroll
        for (int dd = 0; dd < DSUB; ++dd) xd[dd] = (double)xrow[dd];
        const float* cbm = codebooks + (size_t)m * (KCODE * DSUB);

        double bd = 1e300;
        int bi = 0;
        #pragma unroll 1
        for (int cc = 0; cc < 4; ++cc) {
            const int c = l * 4 + cc;                 // lane-local ascending
            const float* cp = cbm + c * DSUB;
            double s = 0.0;
            #pragma unroll
            for (int dd = 0; dd < DSUB; ++dd) {
                double diff = xd[dd] - (double)cp[dd];
                s = fma(diff, diff, s);
            }
            if (s < bd) { bd = s; bi = c; }
        }
        #pragma unroll
        for (int msk = 1; msk <= 32; msk <<= 1) {
            double ob = __shfl_xor(bd, msk);
            int   oi  = __shfl_xor(bi, msk);
            if (ob < bd || (ob == bd && oi < bi)) { bd = ob; bi = oi; }
        }
        if (l < DSUB) out[(size_t)n * DIMS + m * DSUB + l] = cbm[bi * DSUB + l];
    }
}

extern "C" void kernel_launch(void* const* d_in, const int* in_sizes, int n_in,
                              void* d_out, int out_size, void* d_ws, size_t ws_size,
                              hipStream_t stream)
{
    const float* embeds    = (const float*)d_in[0];
    const float* codebooks = (const float*)d_in[1];
    float* out = (float*)d_out;

    unsigned* flag_cnt  = (unsigned*)d_ws;
    unsigned* flag_list = (unsigned*)d_ws + 4;   // 16B offset
    unsigned flag_cap = 0;
    if (ws_size >= 32) {
        size_t cap = (ws_size - 16) / sizeof(unsigned);
        flag_cap = (cap > 0x7FFFFFFFull) ? 0x7FFFFFFFu : (unsigned)cap;
    }

    hipMemsetAsync(d_ws, 0, 16, stream);

    pq_main<<<dim3(2048), dim3(256), 0, stream>>>(
        embeds, codebooks, out, flag_cnt, flag_list, flag_cap);

    pq_refine<<<dim3(256), dim3(256), 0, stream>>>(
        embeds, codebooks, out, flag_cnt, flag_list, flag_cap);
}